// Round 12
// baseline (338.135 us; speedup 1.0000x reference)
//
#include <hip/hip_runtime.h>
#include <hip/hip_bf16.h>
#include <stdint.h>

#define N_NODES  100000
#define N_PAD    100032          // multiple of 64
#define N_EDGES  1600000
#define DIM      128
#define N_LAYERS 3
#define N_GRAPHS 2048

#define BSHIFT   8               // bucket = 256 consecutive dst nodes
#define NBUCKET  391             // ceil(N_NODES / 256)
#define P1CHUNK  4096
#define P1GRID   391             // ceil(N_EDGES / P1CHUNK)

typedef _Float16 f16;
typedef __attribute__((ext_vector_type(4))) _Float16 f16x4;
typedef __attribute__((ext_vector_type(8))) _Float16 f16x8;
typedef __attribute__((ext_vector_type(4))) float f32x4;

#define MFMA16(a, b, c) __builtin_amdgcn_mfma_f32_16x16x32_f16((a), (b), (c), 0, 0, 0)

// ---------------- workspace layout (bytes, 64B-aligned) ----------------
#define OFF_OFFS  0u             // (N_NODES+1) ints
#define OFF_BHT   400064u        // NBUCKET ints (bucket totals)   } one memset
#define OFF_GCUR  401664u        // NBUCKET ints (bucket cursors)  } covers both
#define OFF_BLKH  403264u        // P1GRID*NBUCKET ints (per-block bucket hist)
#define OFF_ESRC  1014848u       // N_EDGES ints
#define OFF_PAIR  7414848u       // N_EDGES u32 packed (src<<8 | d&255)
#define OFF_X16   13814848u      // N_PAD*DIM f16
#define OFF_A16   39423040u      // N_PAD*DIM f16
#define OFF_B16   65031232u      // N_PAD*DIM f16
#define OFF_W1T   90639424u      // 3*128*128 f16 ([l][n][k])
#define OFF_W2T   90737728u      // 3*128*128 f16
// end ~90.8 MB

// ---------------- merged pre-work: cvtX | cvtW | bhist | zero-out ----------------

#define CVTX_BLOCKS 6250         // N_NODES*DIM/8/256
#define CVTW_BLOCKS 384          // 2*3*128*128/256
#define ZERO_BLOCKS 128          // N_GRAPHS*DIM/8/256
#define PRE_GRID    (CVTX_BLOCKS + CVTW_BLOCKS + P1GRID + ZERO_BLOCKS)

__global__ __launch_bounds__(256) void k_pre(
    const float* __restrict__ x, const float* __restrict__ W1, const float* __restrict__ W2,
    f16* __restrict__ x16, f16* __restrict__ W1t, f16* __restrict__ W2t,
    const int* __restrict__ dst, int* __restrict__ btot, int* __restrict__ blkh,
    float* __restrict__ outp)
{
    __shared__ int h[NBUCKET];
    int b = blockIdx.x, tid = threadIdx.x;
    if (b < CVTX_BLOCKS) {
        size_t i = ((size_t)b * 256 + tid) * 8;
        float4 v0 = *(const float4*)&x[i];
        float4 v1 = *(const float4*)&x[i + 4];
        f16x8 o;
        o[0] = (f16)v0.x; o[1] = (f16)v0.y; o[2] = (f16)v0.z; o[3] = (f16)v0.w;
        o[4] = (f16)v1.x; o[5] = (f16)v1.y; o[6] = (f16)v1.z; o[7] = (f16)v1.w;
        *(f16x8*)&x16[i] = o;
    } else if (b < CVTX_BLOCKS + CVTW_BLOCKS) {
        int t = (b - CVTX_BLOCKS) * 256 + tid;       // 98304 total
        bool first = t < 49152;
        const float* W = first ? W1 : W2;
        f16* Wt = first ? W1t : W2t;
        int u = first ? t : t - 49152;
        int l = u >> 14;
        int kn = u & 16383;
        int k = kn >> 7, nn = kn & 127;
        Wt[l * 16384 + nn * 128 + k] = (f16)W[u];
    } else if (b < CVTX_BLOCKS + CVTW_BLOCKS + P1GRID) {
        int bb = b - CVTX_BLOCKS - CVTW_BLOCKS;
        for (int i = tid; i < NBUCKET; i += 256) h[i] = 0;
        __syncthreads();
        int base = bb * P1CHUNK;
        int n = min(P1CHUNK, N_EDGES - base);
        for (int i = tid; i < n; i += 256)
            atomicAdd(&h[dst[base + i] >> BSHIFT], 1);
        __syncthreads();
        for (int i = tid; i < NBUCKET; i += 256) {
            blkh[bb * NBUCKET + i] = h[i];
            atomicAdd(&btot[i], h[i]);
        }
    } else {
        int bb = b - CVTX_BLOCKS - CVTW_BLOCKS - P1GRID;
        size_t i = ((size_t)bb * 256 + tid) * 8;
        float4 z = {0.f, 0.f, 0.f, 0.f};
        *(float4*)&outp[i] = z;
        *(float4*)&outp[i + 4] = z;
    }
}

// ---------------- part1: partition edges into bucket-grouped pairs ----------------
// Each block re-scans btot in LDS; gcur is a zero-based within-bucket cursor
// (zeroed by the same memset as btot).

__global__ __launch_bounds__(256) void k_part1(const int* __restrict__ src, const int* __restrict__ dst,
                                               const int* __restrict__ blkh, const int* __restrict__ btot,
                                               int* __restrict__ gcur, uint32_t* __restrict__ pairs) {
    __shared__ int bs[512];
    __shared__ int gbase[NBUCKET];
    __shared__ int cur[NBUCKET];
    int t = threadIdx.x, b = blockIdx.x;
    bs[t]       = (t < NBUCKET) ? btot[t] : 0;
    bs[t + 256] = (t + 256 < NBUCKET) ? btot[t + 256] : 0;
    __syncthreads();
    for (int off = 1; off < 512; off <<= 1) {
        int a0 = (t >= off) ? bs[t - off] : 0;
        int a1 = (t + 256 >= off) ? bs[t + 256 - off] : 0;
        __syncthreads();
        bs[t] += a0; bs[t + 256] += a1;
        __syncthreads();
    }
    for (int i = t; i < NBUCKET; i += 256) {
        int ex = (i == 0) ? 0 : bs[i - 1];
        int h = blkh[b * NBUCKET + i];
        gbase[i] = ex + atomicAdd(&gcur[i], h);
        cur[i] = 0;
    }
    __syncthreads();
    int base = b * P1CHUNK;
    int n = min(P1CHUNK, N_EDGES - base);
    for (int i = t; i < n; i += 256) {
        int d = dst[base + i], s = src[base + i];
        int bin = d >> BSHIFT;
        int slot = atomicAdd(&cur[bin], 1);
        pairs[gbase[bin] + slot] = ((uint32_t)s << 8) | (uint32_t)(d & 255);
    }
}

// ---------------- part2: per-bucket counting sort -> offs + esrc ----------------

__global__ __launch_bounds__(256) void k_part2(const uint32_t* __restrict__ pairs,
                                               const int* __restrict__ btot,
                                               int* __restrict__ offs, int* __restrict__ esrc) {
    __shared__ int bs[512];
    __shared__ int cnt[256];
    __shared__ int cur[256];
    __shared__ int sc[256];
    int t = threadIdx.x, b = blockIdx.x;
    bs[t]       = (t < NBUCKET) ? btot[t] : 0;
    bs[t + 256] = (t + 256 < NBUCKET) ? btot[t + 256] : 0;
    __syncthreads();
    for (int off = 1; off < 512; off <<= 1) {
        int a0 = (t >= off) ? bs[t - off] : 0;
        int a1 = (t + 256 >= off) ? bs[t + 256 - off] : 0;
        __syncthreads();
        bs[t] += a0; bs[t + 256] += a1;
        __syncthreads();
    }
    int e0 = (b == 0) ? 0 : bs[b - 1];
    int e1 = bs[b];
    if (b == 0 && t == 0) offs[N_NODES] = N_EDGES;
    int n0 = b << BSHIFT;
    int nn = min(256, N_NODES - n0);
    cnt[t] = 0;
    __syncthreads();
    for (int i = e0 + t; i < e1; i += 256)
        atomicAdd(&cnt[pairs[i] & 255], 1);
    __syncthreads();
    int my = cnt[t];
    sc[t] = my;
    __syncthreads();
    for (int off = 1; off < 256; off <<= 1) {
        int v = (t >= off) ? sc[t - off] : 0;
        __syncthreads();
        sc[t] += v;
        __syncthreads();
    }
    int excl = sc[t] - my;
    cur[t] = excl;
    if (t < nn) offs[n0 + t] = e0 + excl;
    __syncthreads();
    for (int i = e0 + t; i < e1; i += 256) {
        uint32_t p = pairs[i];
        int pos = e0 + atomicAdd(&cur[p & 255], 1);
        esrc[pos] = (int)(p >> 8);          // 16KB region, single block -> single XCD
    }
}

// ---------------- fused layer: dynamic gather -> LDS tile -> MLP -> global / pool ----------------
// out = relu(relu((x_i + sum_j x_j) @ W1 + b1) @ W2 + b2)
// BM=64, 512 threads (8 waves). Gather uses dynamic work-stealing: 32 16-lane
// groups pull node slots from an LDS counter (degree-imbalance fix: block time
// = mean work + <=1 node straggle, not max over static groups).
// POOL=true (layer 2): out-tile stays in LDS; per-graph segmented sums are
// atomically added into gsum instead of writing xout.

#define BM 64
#define LDS_K 136    // padded row stride in f16 (272 B)

template <bool POOL>
__global__ __launch_bounds__(512) void k_fused(
    const f16* __restrict__ xin, f16* __restrict__ xout,
    const int* __restrict__ offs, const int* __restrict__ esrc,
    const f16* __restrict__ W1t, const float* __restrict__ b1,
    const f16* __restrict__ W2t, const float* __restrict__ b2,
    const int* __restrict__ batch, float* __restrict__ gsum)
{
    __shared__ __align__(16) f16 tile[BM * LDS_K];
    __shared__ int sbatch[BM];
    __shared__ int wcur;
    int tid  = threadIdx.x;
    int lane = tid & 63;
    int w    = tid >> 6;          // wave 0..7
    int fr   = lane & 15;
    int fg   = lane >> 4;
    int row0 = blockIdx.x * BM;

    if (tid == 0) wcur = 0;
    if (POOL && tid < BM) {
        int node = row0 + tid;
        sbatch[tid] = (node < N_NODES) ? batch[node] : -1;
    }
    __syncthreads();

    // ---- gather: dynamic slots; each 16-lane group gathers one node per pull
    {
        const f16x8* xr = (const f16x8*)xin;   // 16 x 16B chunks per row
        int c = fr;
        int gl = lane & 48;                    // group leader lane
        for (;;) {
            int slot;
            if ((lane & 15) == 0) slot = atomicAdd(&wcur, 1);
            slot = __shfl(slot, gl);
            if (slot >= BM) break;
            int node = row0 + slot;
            f16x8 sum = {(f16)0, (f16)0, (f16)0, (f16)0, (f16)0, (f16)0, (f16)0, (f16)0};
            if (node < N_NODES) {
                sum = xr[(size_t)node * 16 + c];            // self term
                int e0 = offs[node], e1 = offs[node + 1];
                int e = e0;
                for (; e + 8 <= e1; e += 8) {
                    int s0 = esrc[e + 0], s1 = esrc[e + 1], s2 = esrc[e + 2], s3 = esrc[e + 3];
                    int s4 = esrc[e + 4], s5 = esrc[e + 5], s6 = esrc[e + 6], s7 = esrc[e + 7];
                    f16x8 v0 = xr[(size_t)s0 * 16 + c], v1 = xr[(size_t)s1 * 16 + c];
                    f16x8 v2 = xr[(size_t)s2 * 16 + c], v3 = xr[(size_t)s3 * 16 + c];
                    f16x8 v4 = xr[(size_t)s4 * 16 + c], v5 = xr[(size_t)s5 * 16 + c];
                    f16x8 v6 = xr[(size_t)s6 * 16 + c], v7 = xr[(size_t)s7 * 16 + c];
                    sum += (v0 + v1) + (v2 + v3);
                    sum += (v4 + v5) + (v6 + v7);
                }
                if (e < e1) {                               // masked remainder (<=7)
                    int i1 = e + 1, i2 = e + 2, i3 = e + 3, i4 = e + 4, i5 = e + 5, i6 = e + 6, i7 = e + 7;
                    bool k1 = i1 < e1, k2 = i2 < e1, k3 = i3 < e1, k4 = i4 < e1,
                         k5 = i5 < e1, k6 = i6 < e1, k7 = i7 < e1;
                    int s0 = esrc[e];
                    int s1 = esrc[k1 ? i1 : e], s2 = esrc[k2 ? i2 : e], s3 = esrc[k3 ? i3 : e];
                    int s4 = esrc[k4 ? i4 : e], s5 = esrc[k5 ? i5 : e], s6 = esrc[k6 ? i6 : e];
                    int s7 = esrc[k7 ? i7 : e];
                    f16x8 v0 = xr[(size_t)s0 * 16 + c], v1 = xr[(size_t)s1 * 16 + c];
                    f16x8 v2 = xr[(size_t)s2 * 16 + c], v3 = xr[(size_t)s3 * 16 + c];
                    f16x8 v4 = xr[(size_t)s4 * 16 + c], v5 = xr[(size_t)s5 * 16 + c];
                    f16x8 v6 = xr[(size_t)s6 * 16 + c], v7 = xr[(size_t)s7 * 16 + c];
                    sum += v0;
                    if (k1) sum += v1;
                    if (k2) sum += v2;
                    if (k3) sum += v3;
                    if (k4) sum += v4;
                    if (k5) sum += v5;
                    if (k6) sum += v6;
                    if (k7) sum += v7;
                }
            }
            *(f16x8*)&tile[slot * LDS_K + c * 8] = sum;
        }
    }

    // W1 fragments + bias for this wave's 16 cols
    int col = w * 16 + fr;
    f16x8 wf[4];
    float4 bv;
#pragma unroll
    for (int ks = 0; ks < 4; ks++)
        wf[ks] = *(const f16x8*)&W1t[col * DIM + ks * 32 + fg * 8];
    bv = *(const float4*)&b1[w * 16 + fg * 4];
    __syncthreads();

    // ---- GEMM1 (swapped operands): lane holds H[m=mt*16+fr][n=w*16+fg*4+r]
    f32x4 acc[4];
#pragma unroll
    for (int mt = 0; mt < 4; mt++) acc[mt] = (f32x4){0.f, 0.f, 0.f, 0.f};
#pragma unroll
    for (int mt = 0; mt < 4; mt++)
#pragma unroll
        for (int ks = 0; ks < 4; ks++) {
            f16x8 a = *(const f16x8*)&tile[(mt * 16 + fr) * LDS_K + ks * 32 + fg * 8];
            acc[mt] = MFMA16(wf[ks], a, acc[mt]);
        }
    __syncthreads();   // all X reads done before overwriting tile with H

    // H epilogue: relu(acc+b1) -> tile[node][feature], 8B vector writes
#pragma unroll
    for (int mt = 0; mt < 4; mt++) {
        f16x4 hv;
        hv[0] = (f16)fmaxf(acc[mt][0] + bv.x, 0.f);
        hv[1] = (f16)fmaxf(acc[mt][1] + bv.y, 0.f);
        hv[2] = (f16)fmaxf(acc[mt][2] + bv.z, 0.f);
        hv[3] = (f16)fmaxf(acc[mt][3] + bv.w, 0.f);
        *(f16x4*)&tile[(mt * 16 + fr) * LDS_K + w * 16 + fg * 4] = hv;
    }

    // reload fragments with W2/b2 (L2-hot), reuse registers
#pragma unroll
    for (int ks = 0; ks < 4; ks++)
        wf[ks] = *(const f16x8*)&W2t[col * DIM + ks * 32 + fg * 8];
    bv = *(const float4*)&b2[w * 16 + fg * 4];
    __syncthreads();   // H fully written

    // ---- GEMM2 (swapped)
#pragma unroll
    for (int mt = 0; mt < 4; mt++) acc[mt] = (f32x4){0.f, 0.f, 0.f, 0.f};
#pragma unroll
    for (int mt = 0; mt < 4; mt++)
#pragma unroll
        for (int ks = 0; ks < 4; ks++) {
            f16x8 a = *(const f16x8*)&tile[(mt * 16 + fr) * LDS_K + ks * 32 + fg * 8];
            acc[mt] = MFMA16(wf[ks], a, acc[mt]);
        }

    if (!POOL) {
        // store direct to global, 8B per lane
#pragma unroll
        for (int mt = 0; mt < 4; mt++) {
            f16x4 ov;
            ov[0] = (f16)fmaxf(acc[mt][0] + bv.x, 0.f);
            ov[1] = (f16)fmaxf(acc[mt][1] + bv.y, 0.f);
            ov[2] = (f16)fmaxf(acc[mt][2] + bv.z, 0.f);
            ov[3] = (f16)fmaxf(acc[mt][3] + bv.w, 0.f);
            *(f16x4*)&xout[(size_t)(row0 + mt * 16 + fr) * DIM + w * 16 + fg * 4] = ov;
        }
    } else {
        __syncthreads();   // all H reads done before overwriting tile with OUT
#pragma unroll
        for (int mt = 0; mt < 4; mt++) {
            f16x4 ov;
            ov[0] = (f16)fmaxf(acc[mt][0] + bv.x, 0.f);
            ov[1] = (f16)fmaxf(acc[mt][1] + bv.y, 0.f);
            ov[2] = (f16)fmaxf(acc[mt][2] + bv.z, 0.f);
            ov[3] = (f16)fmaxf(acc[mt][3] + bv.w, 0.f);
            *(f16x4*)&tile[(mt * 16 + fr) * LDS_K + w * 16 + fg * 4] = ov;
        }
        __syncthreads();   // out-tile fully written

        // segmented per-graph sums: 4 row-chunks of 16, 128 dims each
        int half = tid >> 7;               // 0..3
        int d = tid & 127;
        int rA = half * 16, rB = rA + 16;
        float s = 0.f;
        int curg = sbatch[rA];
        for (int r = rA; r < rB; r++) {
            int g = sbatch[r];
            if (g != curg) {
                if (curg >= 0) atomicAdd(&gsum[(size_t)curg * DIM + d], s);
                s = 0.f; curg = g;
            }
            if (g >= 0) s += (float)tile[r * LDS_K + d];
        }
        if (curg >= 0) atomicAdd(&gsum[(size_t)curg * DIM + d], s);
    }
}

// ---------------- final divide: out[g][d] /= count(g) ----------------

__global__ void k_div(float* __restrict__ out, const int* __restrict__ batch) {
    int g = blockIdx.x;
    int d = threadIdx.x;
    int lo = 0, hi = N_NODES;
    while (lo < hi) { int m = (lo + hi) >> 1; if (batch[m] < g) lo = m + 1; else hi = m; }
    int start = lo;
    hi = N_NODES;
    while (lo < hi) { int m = (lo + hi) >> 1; if (batch[m] <= g) lo = m + 1; else hi = m; }
    int end = lo;
    float cntf = (float)(end - start);
    out[(size_t)g * DIM + d] /= fmaxf(cntf, 1.f);
}

// ---------------- launch ----------------

extern "C" void kernel_launch(void* const* d_in, const int* in_sizes, int n_in,
                              void* d_out, int out_size, void* d_ws, size_t ws_size,
                              hipStream_t stream) {
    const float* x     = (const float*)d_in[0];
    const int*   ei    = (const int*)d_in[1];
    const int*   batch = (const int*)d_in[2];
    const float* W1    = (const float*)d_in[3];
    const float* b1    = (const float*)d_in[4];
    const float* W2    = (const float*)d_in[5];
    const float* b2    = (const float*)d_in[6];
    const int* srcp = ei;
    const int* dstp = ei + N_EDGES;

    char* ws = (char*)d_ws;
    int*      offs  = (int*)(ws + OFF_OFFS);
    int*      btot  = (int*)(ws + OFF_BHT);
    int*      gcur  = (int*)(ws + OFF_GCUR);
    int*      blkh  = (int*)(ws + OFF_BLKH);
    int*      esrc  = (int*)(ws + OFF_ESRC);
    uint32_t* pairs = (uint32_t*)(ws + OFF_PAIR);
    f16*      x16   = (f16*)(ws + OFF_X16);
    f16*      a16   = (f16*)(ws + OFF_A16);
    f16*      b16   = (f16*)(ws + OFF_B16);
    f16*      w1t   = (f16*)(ws + OFF_W1T);
    f16*      w2t   = (f16*)(ws + OFF_W2T);
    float*    outp  = (float*)d_out;

    // zero btot + gcur in one memset (contiguous), then merged pre-work
    hipMemsetAsync(btot, 0, 3200, stream);
    k_pre<<<PRE_GRID, 256, 0, stream>>>(x, W1, W2, x16, w1t, w2t, dstp, btot, blkh, outp);

    // CSR finish (each block re-scans btot locally; no separate scan kernel)
    k_part1<<<P1GRID, 256, 0, stream>>>(srcp, dstp, blkh, btot, gcur, pairs);
    k_part2<<<NBUCKET, 256, 0, stream>>>(pairs, btot, offs, esrc);

    // 3 fused GIN layers (BM=64, 512 threads, dynamic gather)
    k_fused<false><<<N_PAD / BM, 512, 0, stream>>>(x16, a16, offs, esrc,
                                                   w1t, b1, w2t, b2, batch, outp);
    k_fused<false><<<N_PAD / BM, 512, 0, stream>>>(a16, b16, offs, esrc,
                                                   w1t + 16384, b1 + DIM, w2t + 16384, b2 + DIM, batch, outp);
    k_fused<true><<<N_PAD / BM, 512, 0, stream>>>(b16, a16, offs, esrc,
                                                  w1t + 32768, b1 + 2 * DIM, w2t + 32768, b2 + 2 * DIM, batch, outp);

    // divide by per-graph counts
    k_div<<<N_GRAPHS, DIM, 0, stream>>>(outp, batch);
}

// Round 13
// 336.473 us; speedup vs baseline: 1.0049x; 1.0049x over previous
//
#include <hip/hip_runtime.h>
#include <hip/hip_bf16.h>
#include <stdint.h>

#define N_NODES  100000
#define N_PAD    100032          // multiple of 64
#define N_EDGES  1600000
#define DIM      128
#define N_LAYERS 3
#define N_GRAPHS 2048

#define BSHIFT   8               // bucket = 256 consecutive dst nodes
#define NBUCKET  391             // ceil(N_NODES / 256)
#define P1CHUNK  4096
#define P1GRID   391             // ceil(N_EDGES / P1CHUNK)

typedef _Float16 f16;
typedef __attribute__((ext_vector_type(4))) _Float16 f16x4;
typedef __attribute__((ext_vector_type(8))) _Float16 f16x8;
typedef __attribute__((ext_vector_type(4))) float f32x4;

#define MFMA16(a, b, c) __builtin_amdgcn_mfma_f32_16x16x32_f16((a), (b), (c), 0, 0, 0)

// ---------------- workspace layout (bytes, 64B-aligned) ----------------
#define OFF_OFFS  0u             // (N_NODES+1) ints
#define OFF_BHT   400064u        // NBUCKET ints (bucket totals)   } one memset
#define OFF_GCUR  401664u        // NBUCKET ints (bucket cursors)  } covers both
#define OFF_BLKH  403264u        // P1GRID*NBUCKET ints (per-block bucket hist)
#define OFF_ESRC  1014848u       // N_EDGES ints
#define OFF_PAIR  7414848u       // N_EDGES u32 packed (src<<8 | d&255)
#define OFF_X16   13814848u      // N_PAD*DIM f16
#define OFF_A16   39423040u      // N_PAD*DIM f16
#define OFF_B16   65031232u      // N_PAD*DIM f16
#define OFF_W1T   90639424u      // 3*128*128 f16 ([l][n][k])
#define OFF_W2T   90737728u      // 3*128*128 f16
// end ~90.8 MB

// ---------------- k_bhist: per-chunk bucket histogram ----------------

__global__ __launch_bounds__(256) void k_bhist(const int* __restrict__ dst,
                                               int* __restrict__ btot, int* __restrict__ blkh) {
    __shared__ int h[NBUCKET];
    int tid = threadIdx.x, b = blockIdx.x;
    for (int i = tid; i < NBUCKET; i += 256) h[i] = 0;
    __syncthreads();
    int base = b * P1CHUNK;
    int n = min(P1CHUNK, N_EDGES - base);
    for (int i = tid; i < n; i += 256)
        atomicAdd(&h[dst[base + i] >> BSHIFT], 1);
    __syncthreads();
    for (int i = tid; i < NBUCKET; i += 256) {
        blkh[b * NBUCKET + i] = h[i];
        atomicAdd(&btot[i], h[i]);
    }
}

// ---------------- part1: partition edges into bucket-grouped pairs ----------------
// Each block re-scans btot in LDS; gcur is a zero-based within-bucket cursor
// (zeroed by the same memset as btot).

__global__ __launch_bounds__(256) void k_part1(const int* __restrict__ src, const int* __restrict__ dst,
                                               const int* __restrict__ blkh, const int* __restrict__ btot,
                                               int* __restrict__ gcur, uint32_t* __restrict__ pairs) {
    __shared__ int bs[512];
    __shared__ int gbase[NBUCKET];
    __shared__ int cur[NBUCKET];
    int t = threadIdx.x, b = blockIdx.x;
    bs[t]       = (t < NBUCKET) ? btot[t] : 0;
    bs[t + 256] = (t + 256 < NBUCKET) ? btot[t + 256] : 0;
    __syncthreads();
    for (int off = 1; off < 512; off <<= 1) {
        int a0 = (t >= off) ? bs[t - off] : 0;
        int a1 = (t + 256 >= off) ? bs[t + 256 - off] : 0;
        __syncthreads();
        bs[t] += a0; bs[t + 256] += a1;
        __syncthreads();
    }
    for (int i = t; i < NBUCKET; i += 256) {
        int ex = (i == 0) ? 0 : bs[i - 1];
        int h = blkh[b * NBUCKET + i];
        gbase[i] = ex + atomicAdd(&gcur[i], h);
        cur[i] = 0;
    }
    __syncthreads();
    int base = b * P1CHUNK;
    int n = min(P1CHUNK, N_EDGES - base);
    for (int i = t; i < n; i += 256) {
        int d = dst[base + i], s = src[base + i];
        int bin = d >> BSHIFT;
        int slot = atomicAdd(&cur[bin], 1);
        pairs[gbase[bin] + slot] = ((uint32_t)s << 8) | (uint32_t)(d & 255);
    }
}

// ---------------- merged: part2 | cvtX | cvtW | zero-out ----------------
// part2 blocks first (391), then cvtX (6250), cvtW (384), zero (128).
// cvt/zero are independent of part2 and fill the machine alongside it.

#define M_PART2 NBUCKET
#define M_CVTX  6250             // N_NODES*DIM/8/256
#define M_CVTW  384              // 2*3*128*128/256
#define M_ZERO  128              // N_GRAPHS*DIM/8/256
#define M_GRID  (M_PART2 + M_CVTX + M_CVTW + M_ZERO)

__global__ __launch_bounds__(256) void k_merged(
    const uint32_t* __restrict__ pairs, const int* __restrict__ btot,
    int* __restrict__ offs, int* __restrict__ esrc,
    const float* __restrict__ x, const float* __restrict__ W1, const float* __restrict__ W2,
    f16* __restrict__ x16, f16* __restrict__ W1t, f16* __restrict__ W2t,
    float* __restrict__ outp)
{
    __shared__ int bs[512];
    __shared__ int cnt[256];
    __shared__ int cur[256];
    __shared__ int sc[256];
    int t = threadIdx.x, blk = blockIdx.x;

    if (blk < M_PART2) {
        int b = blk;
        bs[t]       = (t < NBUCKET) ? btot[t] : 0;
        bs[t + 256] = (t + 256 < NBUCKET) ? btot[t + 256] : 0;
        __syncthreads();
        for (int off = 1; off < 512; off <<= 1) {
            int a0 = (t >= off) ? bs[t - off] : 0;
            int a1 = (t + 256 >= off) ? bs[t + 256 - off] : 0;
            __syncthreads();
            bs[t] += a0; bs[t + 256] += a1;
            __syncthreads();
        }
        int e0 = (b == 0) ? 0 : bs[b - 1];
        int e1 = bs[b];
        if (b == 0 && t == 0) offs[N_NODES] = N_EDGES;
        int n0 = b << BSHIFT;
        int nn = min(256, N_NODES - n0);
        cnt[t] = 0;
        __syncthreads();
        for (int i = e0 + t; i < e1; i += 256)
            atomicAdd(&cnt[pairs[i] & 255], 1);
        __syncthreads();
        int my = cnt[t];
        sc[t] = my;
        __syncthreads();
        for (int off = 1; off < 256; off <<= 1) {
            int v = (t >= off) ? sc[t - off] : 0;
            __syncthreads();
            sc[t] += v;
            __syncthreads();
        }
        int excl = sc[t] - my;
        cur[t] = excl;
        if (t < nn) offs[n0 + t] = e0 + excl;
        __syncthreads();
        for (int i = e0 + t; i < e1; i += 256) {
            uint32_t p = pairs[i];
            int pos = e0 + atomicAdd(&cur[p & 255], 1);
            esrc[pos] = (int)(p >> 8);      // 16KB region, single block -> single XCD
        }
    } else if (blk < M_PART2 + M_CVTX) {
        size_t i = ((size_t)(blk - M_PART2) * 256 + t) * 8;
        float4 v0 = *(const float4*)&x[i];
        float4 v1 = *(const float4*)&x[i + 4];
        f16x8 o;
        o[0] = (f16)v0.x; o[1] = (f16)v0.y; o[2] = (f16)v0.z; o[3] = (f16)v0.w;
        o[4] = (f16)v1.x; o[5] = (f16)v1.y; o[6] = (f16)v1.z; o[7] = (f16)v1.w;
        *(f16x8*)&x16[i] = o;
    } else if (blk < M_PART2 + M_CVTX + M_CVTW) {
        int u = (blk - M_PART2 - M_CVTX) * 256 + t;     // 98304 total
        bool first = u < 49152;
        const float* W = first ? W1 : W2;
        f16* Wt = first ? W1t : W2t;
        int v = first ? u : u - 49152;
        int l = v >> 14;
        int kn = v & 16383;
        int k = kn >> 7, nn = kn & 127;
        Wt[l * 16384 + nn * 128 + k] = (f16)W[v];
    } else {
        int bb = blk - M_PART2 - M_CVTX - M_CVTW;
        size_t i = ((size_t)bb * 256 + t) * 8;
        float4 z = {0.f, 0.f, 0.f, 0.f};
        *(float4*)&outp[i] = z;
        *(float4*)&outp[i + 4] = z;
    }
}

// ---------------- fused layer (r9-exact): gather -> LDS tile -> MLP -> global / pool ----------------
// out = relu(relu((x_i + sum_j x_j) @ W1 + b1) @ W2 + b2)
// BM=64, 512 threads (8 waves); group fg of wave w statically owns nodes
// w*8 + b_*4 + fg (b_=0,1), 8-deep edge unroll. Each wave owns 16 GEMM cols.
// NOTE (r10-r12 lesson): shorter per-group runs or dynamic reorder raise
// FETCH 189->270MB (L2 hit-rate loss). Do not change this geometry.

#define BM 64
#define LDS_K 136    // padded row stride in f16 (272 B)

template <bool POOL>
__global__ __launch_bounds__(512) void k_fused(
    const f16* __restrict__ xin, f16* __restrict__ xout,
    const int* __restrict__ offs, const int* __restrict__ esrc,
    const f16* __restrict__ W1t, const float* __restrict__ b1,
    const f16* __restrict__ W2t, const float* __restrict__ b2,
    const int* __restrict__ batch, float* __restrict__ gsum)
{
    __shared__ __align__(16) f16 tile[BM * LDS_K];
    __shared__ int sbatch[BM];
    int tid  = threadIdx.x;
    int lane = tid & 63;
    int w    = tid >> 6;          // wave 0..7
    int fr   = lane & 15;
    int fg   = lane >> 4;
    int row0 = blockIdx.x * BM;

    if (POOL && tid < BM) {
        int node = row0 + tid;
        sbatch[tid] = (node < N_NODES) ? batch[node] : -1;
    }

    // ---- gather phase: group fg of wave w owns nodes w*8 + b_*4 + fg
    {
        const f16x8* xr = (const f16x8*)xin;   // 16 x 16B chunks per row
        int c = fr;
#pragma unroll
        for (int b_ = 0; b_ < 2; b_++) {
            int r = w * 8 + b_ * 4 + fg;
            int node = row0 + r;
            f16x8 sum = {(f16)0, (f16)0, (f16)0, (f16)0, (f16)0, (f16)0, (f16)0, (f16)0};
            if (node < N_NODES) {
                sum = xr[(size_t)node * 16 + c];            // self term
                int e0 = offs[node], e1 = offs[node + 1];
                int e = e0;
                for (; e + 8 <= e1; e += 8) {
                    int s0 = esrc[e + 0], s1 = esrc[e + 1], s2 = esrc[e + 2], s3 = esrc[e + 3];
                    int s4 = esrc[e + 4], s5 = esrc[e + 5], s6 = esrc[e + 6], s7 = esrc[e + 7];
                    f16x8 v0 = xr[(size_t)s0 * 16 + c], v1 = xr[(size_t)s1 * 16 + c];
                    f16x8 v2 = xr[(size_t)s2 * 16 + c], v3 = xr[(size_t)s3 * 16 + c];
                    f16x8 v4 = xr[(size_t)s4 * 16 + c], v5 = xr[(size_t)s5 * 16 + c];
                    f16x8 v6 = xr[(size_t)s6 * 16 + c], v7 = xr[(size_t)s7 * 16 + c];
                    sum += (v0 + v1) + (v2 + v3);
                    sum += (v4 + v5) + (v6 + v7);
                }
                if (e < e1) {                               // masked remainder (<=7)
                    int i1 = e + 1, i2 = e + 2, i3 = e + 3, i4 = e + 4, i5 = e + 5, i6 = e + 6, i7 = e + 7;
                    bool k1 = i1 < e1, k2 = i2 < e1, k3 = i3 < e1, k4 = i4 < e1,
                         k5 = i5 < e1, k6 = i6 < e1, k7 = i7 < e1;
                    int s0 = esrc[e];
                    int s1 = esrc[k1 ? i1 : e], s2 = esrc[k2 ? i2 : e], s3 = esrc[k3 ? i3 : e];
                    int s4 = esrc[k4 ? i4 : e], s5 = esrc[k5 ? i5 : e], s6 = esrc[k6 ? i6 : e];
                    int s7 = esrc[k7 ? i7 : e];
                    f16x8 v0 = xr[(size_t)s0 * 16 + c], v1 = xr[(size_t)s1 * 16 + c];
                    f16x8 v2 = xr[(size_t)s2 * 16 + c], v3 = xr[(size_t)s3 * 16 + c];
                    f16x8 v4 = xr[(size_t)s4 * 16 + c], v5 = xr[(size_t)s5 * 16 + c];
                    f16x8 v6 = xr[(size_t)s6 * 16 + c], v7 = xr[(size_t)s7 * 16 + c];
                    sum += v0;
                    if (k1) sum += v1;
                    if (k2) sum += v2;
                    if (k3) sum += v3;
                    if (k4) sum += v4;
                    if (k5) sum += v5;
                    if (k6) sum += v6;
                    if (k7) sum += v7;
                }
            }
            *(f16x8*)&tile[r * LDS_K + c * 8] = sum;
        }
    }

    // W1 fragments + bias for this wave's 16 cols (overlaps gather of other waves)
    int col = w * 16 + fr;
    f16x8 wf[4];
    float4 bv;
#pragma unroll
    for (int ks = 0; ks < 4; ks++)
        wf[ks] = *(const f16x8*)&W1t[col * DIM + ks * 32 + fg * 8];
    bv = *(const float4*)&b1[w * 16 + fg * 4];
    __syncthreads();

    // ---- GEMM1 (swapped operands): lane holds H[m=mt*16+fr][n=w*16+fg*4+r]
    f32x4 acc[4];
#pragma unroll
    for (int mt = 0; mt < 4; mt++) acc[mt] = (f32x4){0.f, 0.f, 0.f, 0.f};
#pragma unroll
    for (int mt = 0; mt < 4; mt++)
#pragma unroll
        for (int ks = 0; ks < 4; ks++) {
            f16x8 a = *(const f16x8*)&tile[(mt * 16 + fr) * LDS_K + ks * 32 + fg * 8];
            acc[mt] = MFMA16(wf[ks], a, acc[mt]);
        }
    __syncthreads();   // all X reads done before overwriting tile with H

    // H epilogue: relu(acc+b1) -> tile[node][feature], 8B vector writes
#pragma unroll
    for (int mt = 0; mt < 4; mt++) {
        f16x4 hv;
        hv[0] = (f16)fmaxf(acc[mt][0] + bv.x, 0.f);
        hv[1] = (f16)fmaxf(acc[mt][1] + bv.y, 0.f);
        hv[2] = (f16)fmaxf(acc[mt][2] + bv.z, 0.f);
        hv[3] = (f16)fmaxf(acc[mt][3] + bv.w, 0.f);
        *(f16x4*)&tile[(mt * 16 + fr) * LDS_K + w * 16 + fg * 4] = hv;
    }

    // reload fragments with W2/b2 (L2-hot), reuse registers
#pragma unroll
    for (int ks = 0; ks < 4; ks++)
        wf[ks] = *(const f16x8*)&W2t[col * DIM + ks * 32 + fg * 8];
    bv = *(const float4*)&b2[w * 16 + fg * 4];
    __syncthreads();   // H fully written

    // ---- GEMM2 (swapped)
#pragma unroll
    for (int mt = 0; mt < 4; mt++) acc[mt] = (f32x4){0.f, 0.f, 0.f, 0.f};
#pragma unroll
    for (int mt = 0; mt < 4; mt++)
#pragma unroll
        for (int ks = 0; ks < 4; ks++) {
            f16x8 a = *(const f16x8*)&tile[(mt * 16 + fr) * LDS_K + ks * 32 + fg * 8];
            acc[mt] = MFMA16(wf[ks], a, acc[mt]);
        }

    if (!POOL) {
        // store direct to global, 8B per lane
#pragma unroll
        for (int mt = 0; mt < 4; mt++) {
            f16x4 ov;
            ov[0] = (f16)fmaxf(acc[mt][0] + bv.x, 0.f);
            ov[1] = (f16)fmaxf(acc[mt][1] + bv.y, 0.f);
            ov[2] = (f16)fmaxf(acc[mt][2] + bv.z, 0.f);
            ov[3] = (f16)fmaxf(acc[mt][3] + bv.w, 0.f);
            *(f16x4*)&xout[(size_t)(row0 + mt * 16 + fr) * DIM + w * 16 + fg * 4] = ov;
        }
    } else {
        __syncthreads();   // all H reads done before overwriting tile with OUT
#pragma unroll
        for (int mt = 0; mt < 4; mt++) {
            f16x4 ov;
            ov[0] = (f16)fmaxf(acc[mt][0] + bv.x, 0.f);
            ov[1] = (f16)fmaxf(acc[mt][1] + bv.y, 0.f);
            ov[2] = (f16)fmaxf(acc[mt][2] + bv.z, 0.f);
            ov[3] = (f16)fmaxf(acc[mt][3] + bv.w, 0.f);
            *(f16x4*)&tile[(mt * 16 + fr) * LDS_K + w * 16 + fg * 4] = ov;
        }
        __syncthreads();   // out-tile fully written

        // segmented per-graph sums: 4 row-chunks of 16, 128 dims each
        int half = tid >> 7;               // 0..3
        int d = tid & 127;
        int rA = half * 16, rB = rA + 16;
        float s = 0.f;
        int curg = sbatch[rA];
        for (int r = rA; r < rB; r++) {
            int g = sbatch[r];
            if (g != curg) {
                if (curg >= 0) atomicAdd(&gsum[(size_t)curg * DIM + d], s);
                s = 0.f; curg = g;
            }
            if (g >= 0) s += (float)tile[r * LDS_K + d];
        }
        if (curg >= 0) atomicAdd(&gsum[(size_t)curg * DIM + d], s);
    }
}

// ---------------- final divide: out[g][d] /= count(g) ----------------

__global__ void k_div(float* __restrict__ out, const int* __restrict__ batch) {
    int g = blockIdx.x;
    int d = threadIdx.x;
    int lo = 0, hi = N_NODES;
    while (lo < hi) { int m = (lo + hi) >> 1; if (batch[m] < g) lo = m + 1; else hi = m; }
    int start = lo;
    hi = N_NODES;
    while (lo < hi) { int m = (lo + hi) >> 1; if (batch[m] <= g) lo = m + 1; else hi = m; }
    int end = lo;
    float cntf = (float)(end - start);
    out[(size_t)g * DIM + d] /= fmaxf(cntf, 1.f);
}

// ---------------- launch ----------------

extern "C" void kernel_launch(void* const* d_in, const int* in_sizes, int n_in,
                              void* d_out, int out_size, void* d_ws, size_t ws_size,
                              hipStream_t stream) {
    const float* x     = (const float*)d_in[0];
    const int*   ei    = (const int*)d_in[1];
    const int*   batch = (const int*)d_in[2];
    const float* W1    = (const float*)d_in[3];
    const float* b1    = (const float*)d_in[4];
    const float* W2    = (const float*)d_in[5];
    const float* b2    = (const float*)d_in[6];
    const int* srcp = ei;
    const int* dstp = ei + N_EDGES;

    char* ws = (char*)d_ws;
    int*      offs  = (int*)(ws + OFF_OFFS);
    int*      btot  = (int*)(ws + OFF_BHT);
    int*      gcur  = (int*)(ws + OFF_GCUR);
    int*      blkh  = (int*)(ws + OFF_BLKH);
    int*      esrc  = (int*)(ws + OFF_ESRC);
    uint32_t* pairs = (uint32_t*)(ws + OFF_PAIR);
    f16*      x16   = (f16*)(ws + OFF_X16);
    f16*      a16   = (f16*)(ws + OFF_A16);
    f16*      b16   = (f16*)(ws + OFF_B16);
    f16*      w1t   = (f16*)(ws + OFF_W1T);
    f16*      w2t   = (f16*)(ws + OFF_W2T);
    float*    outp  = (float*)d_out;

    // zero btot + gcur (contiguous) in one memset
    hipMemsetAsync(btot, 0, 3200, stream);

    // CSR: bhist -> part1 -> merged{part2 | cvtX | cvtW | zero-out}
    k_bhist<<<P1GRID, 256, 0, stream>>>(dstp, btot, blkh);
    k_part1<<<P1GRID, 256, 0, stream>>>(srcp, dstp, blkh, btot, gcur, pairs);
    k_merged<<<M_GRID, 256, 0, stream>>>(pairs, btot, offs, esrc,
                                         x, W1, W2, x16, w1t, w2t, outp);

    // 3 fused GIN layers (r9-exact geometry)
    k_fused<false><<<N_PAD / BM, 512, 0, stream>>>(x16, a16, offs, esrc,
                                                   w1t, b1, w2t, b2, batch, outp);
    k_fused<false><<<N_PAD / BM, 512, 0, stream>>>(a16, b16, offs, esrc,
                                                   w1t + 16384, b1 + DIM, w2t + 16384, b2 + DIM, batch, outp);
    k_fused<true><<<N_PAD / BM, 512, 0, stream>>>(b16, a16, offs, esrc,
                                                  w1t + 32768, b1 + 2 * DIM, w2t + 32768, b2 + 2 * DIM, batch, outp);

    // divide by per-graph counts
    k_div<<<N_GRAPHS, DIM, 0, stream>>>(outp, batch);
}

// Round 14
// 287.401 us; speedup vs baseline: 1.1765x; 1.1707x over previous
//
#include <hip/hip_runtime.h>
#include <hip/hip_bf16.h>
#include <stdint.h>

#define N_NODES  100000
#define N_PAD    100032          // padded to multiple of 64 for MLP tiles
#define N_EDGES  1600000
#define DIM      128
#define N_LAYERS 3
#define N_GRAPHS 2048

#define BSHIFT   8               // bucket = 256 consecutive dst nodes
#define NBUCKET  391             // ceil(N_NODES / 256)
#define P1CHUNK  4096
#define P1GRID   391             // ceil(N_EDGES / P1CHUNK)

typedef _Float16 f16;
typedef __attribute__((ext_vector_type(4))) _Float16 f16x4;
typedef __attribute__((ext_vector_type(8))) _Float16 f16x8;
typedef __attribute__((ext_vector_type(4))) float f32x4;

#define MFMA16(a, b, c) __builtin_amdgcn_mfma_f32_16x16x32_f16((a), (b), (c), 0, 0, 0)

// ---------------- workspace layout (bytes, 64B-aligned) ----------------
#define OFF_OFFS  0u             // (N_NODES+1) ints
#define OFF_BHT   400064u        // NBUCKET ints (bucket totals)
#define OFF_BST   401664u        // NBUCKET+1 ints (bucket starts)
#define OFF_GCUR  403264u        // NBUCKET ints (bucket cursors)
#define OFF_BLKH  404864u        // P1GRID*NBUCKET ints (per-block bucket hist)
#define OFF_ESRC  1016448u       // N_EDGES ints
#define OFF_PAIR  7416448u       // N_EDGES u32 packed (src<<8 | d&255)
#define OFF_X16   13816448u      // N_PAD*DIM f16
#define OFF_A16   39424640u      // N_PAD*DIM f16
#define OFF_B16   65032832u      // N_PAD*DIM f16
#define OFF_W1T   90641024u      // 3*128*128 f16 ([l][n][k])
#define OFF_W2T   90739328u      // 3*128*128 f16
// end ~90.8 MB

// ---------------- merged pre-work: cvtX | cvtW | bhist | zero-out ----------------

#define CVTX_BLOCKS 6250         // N_NODES*DIM/8/256
#define CVTW_BLOCKS 384          // 2*3*128*128/256
#define ZERO_BLOCKS 128          // N_GRAPHS*DIM/8/256
#define PRE_GRID    (CVTX_BLOCKS + CVTW_BLOCKS + P1GRID + ZERO_BLOCKS)

__global__ __launch_bounds__(256) void k_pre(
    const float* __restrict__ x, const float* __restrict__ W1, const float* __restrict__ W2,
    f16* __restrict__ x16, f16* __restrict__ W1t, f16* __restrict__ W2t,
    const int* __restrict__ dst, int* __restrict__ btot, int* __restrict__ blkh,
    float* __restrict__ outp)
{
    __shared__ int h[NBUCKET];
    int b = blockIdx.x, tid = threadIdx.x;
    if (b < CVTX_BLOCKS) {
        size_t i = ((size_t)b * 256 + tid) * 8;
        float4 v0 = *(const float4*)&x[i];
        float4 v1 = *(const float4*)&x[i + 4];
        f16x8 o;
        o[0] = (f16)v0.x; o[1] = (f16)v0.y; o[2] = (f16)v0.z; o[3] = (f16)v0.w;
        o[4] = (f16)v1.x; o[5] = (f16)v1.y; o[6] = (f16)v1.z; o[7] = (f16)v1.w;
        *(f16x8*)&x16[i] = o;
    } else if (b < CVTX_BLOCKS + CVTW_BLOCKS) {
        int t = (b - CVTX_BLOCKS) * 256 + tid;       // 98304 total
        bool first = t < 49152;
        const float* W = first ? W1 : W2;
        f16* Wt = first ? W1t : W2t;
        int u = first ? t : t - 49152;
        int l = u >> 14;
        int kn = u & 16383;
        int k = kn >> 7, nn = kn & 127;
        Wt[l * 16384 + nn * 128 + k] = (f16)W[u];
    } else if (b < CVTX_BLOCKS + CVTW_BLOCKS + P1GRID) {
        int bb = b - CVTX_BLOCKS - CVTW_BLOCKS;
        for (int i = tid; i < NBUCKET; i += 256) h[i] = 0;
        __syncthreads();
        int base = bb * P1CHUNK;
        int n = min(P1CHUNK, N_EDGES - base);
        for (int i = tid; i < n; i += 256)
            atomicAdd(&h[dst[base + i] >> BSHIFT], 1);
        __syncthreads();
        for (int i = tid; i < NBUCKET; i += 256) {
            blkh[bb * NBUCKET + i] = h[i];
            atomicAdd(&btot[i], h[i]);
        }
    } else {
        int bb = b - CVTX_BLOCKS - CVTW_BLOCKS - P1GRID;
        size_t i = ((size_t)bb * 256 + tid) * 8;
        float4 z = {0.f, 0.f, 0.f, 0.f};
        *(float4*)&outp[i] = z;
        *(float4*)&outp[i + 4] = z;
    }
}

// 1-block parallel exclusive scan of btot[NBUCKET] (padded to 512)
__global__ __launch_bounds__(256) void k_bscan(const int* __restrict__ btot,
                                               int* __restrict__ bstart,
                                               int* __restrict__ gcursor,
                                               int* __restrict__ offs) {
    __shared__ int s[512];
    int t = threadIdx.x;
    s[t]       = (t < NBUCKET) ? btot[t] : 0;
    s[t + 256] = (t + 256 < NBUCKET) ? btot[t + 256] : 0;
    __syncthreads();
    for (int off = 1; off < 512; off <<= 1) {
        int a0 = (t >= off) ? s[t - off] : 0;
        int a1 = (t + 256 >= off) ? s[t + 256 - off] : 0;
        __syncthreads();
        s[t] += a0; s[t + 256] += a1;
        __syncthreads();
    }
    int e0 = (t == 0) ? 0 : s[t - 1];     // exclusive starts
    int e1 = s[t + 255];
    if (t < NBUCKET) { bstart[t] = e0; gcursor[t] = e0; }
    int idx = t + 256;
    if (idx <= NBUCKET) { bstart[idx] = e1; if (idx < NBUCKET) gcursor[idx] = e1; }
    if (t == 0) offs[N_NODES] = N_EDGES;
}

__global__ __launch_bounds__(256) void k_part1(const int* __restrict__ src, const int* __restrict__ dst,
                                               const int* __restrict__ blkh, int* __restrict__ gcursor,
                                               uint32_t* __restrict__ pairs) {
    __shared__ int gbase[NBUCKET];
    __shared__ int cur[NBUCKET];
    int tid = threadIdx.x, b = blockIdx.x;
    for (int i = tid; i < NBUCKET; i += 256) {
        int h = blkh[b * NBUCKET + i];
        gbase[i] = atomicAdd(&gcursor[i], h);
        cur[i] = 0;
    }
    __syncthreads();
    int base = b * P1CHUNK;
    int n = min(P1CHUNK, N_EDGES - base);
    for (int i = tid; i < n; i += 256) {
        int d = dst[base + i], s = src[base + i];
        int bin = d >> BSHIFT;
        int slot = atomicAdd(&cur[bin], 1);
        pairs[gbase[bin] + slot] = ((uint32_t)s << 8) | (uint32_t)(d & 255);
    }
}

__global__ __launch_bounds__(256) void k_part2(const uint32_t* __restrict__ pairs,
                                               const int* __restrict__ bstart,
                                               int* __restrict__ offs, int* __restrict__ esrc) {
    __shared__ int cnt[256];
    __shared__ int cur[256];
    __shared__ int sc[256];
    int t = threadIdx.x, b = blockIdx.x;
    int n0 = b << BSHIFT;
    int nn = min(256, N_NODES - n0);
    int e0 = bstart[b], e1 = bstart[b + 1];
    cnt[t] = 0;
    __syncthreads();
    for (int i = e0 + t; i < e1; i += 256)
        atomicAdd(&cnt[pairs[i] & 255], 1);
    __syncthreads();
    int my = cnt[t];
    sc[t] = my;
    __syncthreads();
    for (int off = 1; off < 256; off <<= 1) {
        int v = (t >= off) ? sc[t - off] : 0;
        __syncthreads();
        sc[t] += v;
        __syncthreads();
    }
    int excl = sc[t] - my;
    cur[t] = excl;
    if (t < nn) offs[n0 + t] = e0 + excl;
    __syncthreads();
    for (int i = e0 + t; i < e1; i += 256) {
        uint32_t p = pairs[i];
        int pos = e0 + atomicAdd(&cur[p & 255], 1);
        esrc[pos] = (int)(p >> 8);          // 16KB region, single block -> single XCD
    }
}

// ---------------- fused layer: gather -> LDS tile -> MLP -> global / pool ----------------
// out = relu(relu((x_i + sum_j x_j) @ W1 + b1) @ W2 + b2)
// 512 threads (8 waves); wave w gathers 8 nodes (4 x 16-lane groups, 2 serial,
// 8-deep unroll), then owns 16 output columns in both GEMMs.
// POOL=true (layer 2): out-tile stays in LDS; segmented per-graph sums are
// atomically added into gsum instead of writing xout.
// NOTE (r10-r13 lesson): do NOT change this geometry or the CSR path; both
// perturbations raised gather FETCH 189->273MB.

#define BM 64
#define LDS_K 136    // padded row stride in f16 (272 B)

template <bool POOL>
__global__ __launch_bounds__(512) void k_fused(
    const f16* __restrict__ xin, f16* __restrict__ xout,
    const int* __restrict__ offs, const int* __restrict__ esrc,
    const f16* __restrict__ W1t, const float* __restrict__ b1,
    const f16* __restrict__ W2t, const float* __restrict__ b2,
    const int* __restrict__ batch, float* __restrict__ gsum)
{
    __shared__ __align__(16) f16 tile[BM * LDS_K];
    __shared__ int sbatch[BM];
    int tid  = threadIdx.x;
    int lane = tid & 63;
    int w    = tid >> 6;          // wave 0..7
    int fr   = lane & 15;
    int fg   = lane >> 4;
    int row0 = blockIdx.x * BM;

    if (POOL && tid < BM) {
        int node = row0 + tid;
        sbatch[tid] = (node < N_NODES) ? batch[node] : -1;
    }

    // ---- gather phase: group fg of wave w owns nodes w*8 + b_*4 + fg
    {
        const f16x8* xr = (const f16x8*)xin;   // 16 x 16B chunks per row
        int c = fr;
#pragma unroll
        for (int b_ = 0; b_ < 2; b_++) {
            int r = w * 8 + b_ * 4 + fg;
            int node = row0 + r;
            f16x8 sum = {(f16)0, (f16)0, (f16)0, (f16)0, (f16)0, (f16)0, (f16)0, (f16)0};
            if (node < N_NODES) {
                sum = xr[(size_t)node * 16 + c];            // self term
                int e0 = offs[node], e1 = offs[node + 1];
                int e = e0;
                for (; e + 8 <= e1; e += 8) {
                    int s0 = esrc[e + 0], s1 = esrc[e + 1], s2 = esrc[e + 2], s3 = esrc[e + 3];
                    int s4 = esrc[e + 4], s5 = esrc[e + 5], s6 = esrc[e + 6], s7 = esrc[e + 7];
                    f16x8 v0 = xr[(size_t)s0 * 16 + c], v1 = xr[(size_t)s1 * 16 + c];
                    f16x8 v2 = xr[(size_t)s2 * 16 + c], v3 = xr[(size_t)s3 * 16 + c];
                    f16x8 v4 = xr[(size_t)s4 * 16 + c], v5 = xr[(size_t)s5 * 16 + c];
                    f16x8 v6 = xr[(size_t)s6 * 16 + c], v7 = xr[(size_t)s7 * 16 + c];
                    sum += (v0 + v1) + (v2 + v3);
                    sum += (v4 + v5) + (v6 + v7);
                }
                if (e < e1) {                               // masked remainder (<=7)
                    int i1 = e + 1, i2 = e + 2, i3 = e + 3, i4 = e + 4, i5 = e + 5, i6 = e + 6, i7 = e + 7;
                    bool k1 = i1 < e1, k2 = i2 < e1, k3 = i3 < e1, k4 = i4 < e1,
                         k5 = i5 < e1, k6 = i6 < e1, k7 = i7 < e1;
                    int s0 = esrc[e];
                    int s1 = esrc[k1 ? i1 : e], s2 = esrc[k2 ? i2 : e], s3 = esrc[k3 ? i3 : e];
                    int s4 = esrc[k4 ? i4 : e], s5 = esrc[k5 ? i5 : e], s6 = esrc[k6 ? i6 : e];
                    int s7 = esrc[k7 ? i7 : e];
                    f16x8 v0 = xr[(size_t)s0 * 16 + c], v1 = xr[(size_t)s1 * 16 + c];
                    f16x8 v2 = xr[(size_t)s2 * 16 + c], v3 = xr[(size_t)s3 * 16 + c];
                    f16x8 v4 = xr[(size_t)s4 * 16 + c], v5 = xr[(size_t)s5 * 16 + c];
                    f16x8 v6 = xr[(size_t)s6 * 16 + c], v7 = xr[(size_t)s7 * 16 + c];
                    sum += v0;
                    if (k1) sum += v1;
                    if (k2) sum += v2;
                    if (k3) sum += v3;
                    if (k4) sum += v4;
                    if (k5) sum += v5;
                    if (k6) sum += v6;
                    if (k7) sum += v7;
                }
            }
            *(f16x8*)&tile[r * LDS_K + c * 8] = sum;
        }
    }

    // W1 fragments + bias for this wave's 16 cols (overlaps gather of other waves)
    int col = w * 16 + fr;
    f16x8 wf[4];
    float4 bv;
#pragma unroll
    for (int ks = 0; ks < 4; ks++)
        wf[ks] = *(const f16x8*)&W1t[col * DIM + ks * 32 + fg * 8];
    bv = *(const float4*)&b1[w * 16 + fg * 4];
    __syncthreads();

    // ---- GEMM1 (swapped operands)
    f32x4 acc[4];
#pragma unroll
    for (int mt = 0; mt < 4; mt++) acc[mt] = (f32x4){0.f, 0.f, 0.f, 0.f};
#pragma unroll
    for (int mt = 0; mt < 4; mt++)
#pragma unroll
        for (int ks = 0; ks < 4; ks++) {
            f16x8 a = *(const f16x8*)&tile[(mt * 16 + fr) * LDS_K + ks * 32 + fg * 8];
            acc[mt] = MFMA16(wf[ks], a, acc[mt]);
        }
    __syncthreads();   // all X reads done before overwriting tile with H

    // H epilogue: relu(acc+b1) -> tile[node][feature], 8B vector writes
#pragma unroll
    for (int mt = 0; mt < 4; mt++) {
        f16x4 hv;
        hv[0] = (f16)fmaxf(acc[mt][0] + bv.x, 0.f);
        hv[1] = (f16)fmaxf(acc[mt][1] + bv.y, 0.f);
        hv[2] = (f16)fmaxf(acc[mt][2] + bv.z, 0.f);
        hv[3] = (f16)fmaxf(acc[mt][3] + bv.w, 0.f);
        *(f16x4*)&tile[(mt * 16 + fr) * LDS_K + w * 16 + fg * 4] = hv;
    }

    // reload fragments with W2/b2 (L2-hot), reuse registers
#pragma unroll
    for (int ks = 0; ks < 4; ks++)
        wf[ks] = *(const f16x8*)&W2t[col * DIM + ks * 32 + fg * 8];
    bv = *(const float4*)&b2[w * 16 + fg * 4];
    __syncthreads();   // H fully written

    // ---- GEMM2 (swapped)
#pragma unroll
    for (int mt = 0; mt < 4; mt++) acc[mt] = (f32x4){0.f, 0.f, 0.f, 0.f};
#pragma unroll
    for (int mt = 0; mt < 4; mt++)
#pragma unroll
        for (int ks = 0; ks < 4; ks++) {
            f16x8 a = *(const f16x8*)&tile[(mt * 16 + fr) * LDS_K + ks * 32 + fg * 8];
            acc[mt] = MFMA16(wf[ks], a, acc[mt]);
        }

    if (!POOL) {
        // store direct to global, 8B per lane
#pragma unroll
        for (int mt = 0; mt < 4; mt++) {
            f16x4 ov;
            ov[0] = (f16)fmaxf(acc[mt][0] + bv.x, 0.f);
            ov[1] = (f16)fmaxf(acc[mt][1] + bv.y, 0.f);
            ov[2] = (f16)fmaxf(acc[mt][2] + bv.z, 0.f);
            ov[3] = (f16)fmaxf(acc[mt][3] + bv.w, 0.f);
            *(f16x4*)&xout[(size_t)(row0 + mt * 16 + fr) * DIM + w * 16 + fg * 4] = ov;
        }
    } else {
        __syncthreads();   // all H reads done before overwriting tile with OUT
#pragma unroll
        for (int mt = 0; mt < 4; mt++) {
            f16x4 ov;
            ov[0] = (f16)fmaxf(acc[mt][0] + bv.x, 0.f);
            ov[1] = (f16)fmaxf(acc[mt][1] + bv.y, 0.f);
            ov[2] = (f16)fmaxf(acc[mt][2] + bv.z, 0.f);
            ov[3] = (f16)fmaxf(acc[mt][3] + bv.w, 0.f);
            *(f16x4*)&tile[(mt * 16 + fr) * LDS_K + w * 16 + fg * 4] = ov;
        }
        __syncthreads();   // out-tile fully written

        // segmented per-graph sums: 4 row-chunks of 16, 128 dims each
        int half = tid >> 7;               // 0..3
        int d = tid & 127;
        int rA = half * 16, rB = rA + 16;
        float s = 0.f;
        int curg = sbatch[rA];
        for (int r = rA; r < rB; r++) {
            int g = sbatch[r];
            if (g != curg) {
                if (curg >= 0) atomicAdd(&gsum[(size_t)curg * DIM + d], s);
                s = 0.f; curg = g;
            }
            if (g >= 0) s += (float)tile[r * LDS_K + d];
        }
        if (curg >= 0) atomicAdd(&gsum[(size_t)curg * DIM + d], s);
    }
}

// ---------------- final divide: out[g][d] /= count(g) ----------------

__global__ void k_div(float* __restrict__ out, const int* __restrict__ batch) {
    int g = blockIdx.x;
    int d = threadIdx.x;
    int lo = 0, hi = N_NODES;
    while (lo < hi) { int m = (lo + hi) >> 1; if (batch[m] < g) lo = m + 1; else hi = m; }
    int start = lo;
    hi = N_NODES;
    while (lo < hi) { int m = (lo + hi) >> 1; if (batch[m] <= g) lo = m + 1; else hi = m; }
    int end = lo;
    float cntf = (float)(end - start);
    out[(size_t)g * DIM + d] /= fmaxf(cntf, 1.f);
}

// ---------------- launch ----------------

extern "C" void kernel_launch(void* const* d_in, const int* in_sizes, int n_in,
                              void* d_out, int out_size, void* d_ws, size_t ws_size,
                              hipStream_t stream) {
    const float* x     = (const float*)d_in[0];
    const int*   ei    = (const int*)d_in[1];
    const int*   batch = (const int*)d_in[2];
    const float* W1    = (const float*)d_in[3];
    const float* b1    = (const float*)d_in[4];
    const float* W2    = (const float*)d_in[5];
    const float* b2    = (const float*)d_in[6];
    const int* srcp = ei;
    const int* dstp = ei + N_EDGES;

    char* ws = (char*)d_ws;
    int*      offs  = (int*)(ws + OFF_OFFS);
    int*      btot  = (int*)(ws + OFF_BHT);
    int*      bst   = (int*)(ws + OFF_BST);
    int*      gcur  = (int*)(ws + OFF_GCUR);
    int*      blkh  = (int*)(ws + OFF_BLKH);
    int*      esrc  = (int*)(ws + OFF_ESRC);
    uint32_t* pairs = (uint32_t*)(ws + OFF_PAIR);
    f16*      x16   = (f16*)(ws + OFF_X16);
    f16*      a16   = (f16*)(ws + OFF_A16);
    f16*      b16   = (f16*)(ws + OFF_B16);
    f16*      w1t   = (f16*)(ws + OFF_W1T);
    f16*      w2t   = (f16*)(ws + OFF_W2T);
    float*    outp  = (float*)d_out;

    // pre-work: btot zero, then cvtX | cvtW | bhist | zero-out in one kernel
    hipMemsetAsync(btot, 0, NBUCKET * sizeof(int), stream);
    k_pre<<<PRE_GRID, 256, 0, stream>>>(x, W1, W2, x16, w1t, w2t, dstp, btot, blkh, outp);

    // CSR finish
    k_bscan<<<1, 256, 0, stream>>>(btot, bst, gcur, offs);
    k_part1<<<P1GRID, 256, 0, stream>>>(srcp, dstp, blkh, gcur, pairs);
    k_part2<<<NBUCKET, 256, 0, stream>>>(pairs, bst, offs, esrc);

    // 3 fused GIN layers
    k_fused<false><<<N_PAD / BM, 512, 0, stream>>>(x16, a16, offs, esrc,
                                                   w1t, b1, w2t, b2, batch, outp);
    k_fused<false><<<N_PAD / BM, 512, 0, stream>>>(a16, b16, offs, esrc,
                                                   w1t + 16384, b1 + DIM, w2t + 16384, b2 + DIM, batch, outp);
    k_fused<true><<<N_PAD / BM, 512, 0, stream>>>(b16, a16, offs, esrc,
                                                  w1t + 32768, b1 + 2 * DIM, w2t + 32768, b2 + 2 * DIM, batch, outp);

    // divide by per-graph counts
    k_div<<<N_GRAPHS, DIM, 0, stream>>>(outp, batch);
}